// Round 12
// baseline (414.149 us; speedup 1.0000x reference)
//
#include <hip/hip_runtime.h>
#include <hip/hip_bf16.h>

typedef float f32x4 __attribute__((ext_vector_type(4)));
typedef float f32x16 __attribute__((ext_vector_type(16)));
typedef _Float16 half8 __attribute__((ext_vector_type(8)));
typedef __bf16 bf16x8 __attribute__((ext_vector_type(8)));
typedef __bf16 bf16x4 __attribute__((ext_vector_type(4)));
typedef unsigned short ushort_t;

constexpr int Bb = 16, Ss = 4096, Dd = 64;
constexpr int KBLK = 32, QBLK = 256;
constexpr int NT = Ss / KBLK;   // 128 tiles, 4 parities -> 32 iterations
constexpr float kLOG2E = 1.44269504088896340736f;
constexpr float DEFER_THR = 10.0f;   // exp2(10)=1024 max P; fp16-safe

constexpr int KP_BLOCKS = (Bb * Ss * Dd / 8) / 256;      // 2048
constexpr int VT_BLOCKS = (Bb * Dd * (Ss / 32)) / 256;   // 512

#define GLOAD_LDS16(gp, lp)                                                              \
    __builtin_amdgcn_global_load_lds(                                                    \
        (const __attribute__((address_space(1))) void*)(gp),                             \
        (__attribute__((address_space(3))) void*)(lp), 16, 0, 0)

// ------- pre-pass: K -> f16 hi/lo [b][s][d]; V -> Vt f16 [b][d][s] (round-6 verified) -
__global__ __launch_bounds__(256)
void prep_f16s(const float* __restrict__ K, const float* __restrict__ V,
               _Float16* __restrict__ Khi, _Float16* __restrict__ Klo,
               _Float16* __restrict__ Vt)
{
    const int bid = blockIdx.x;
    if (bid < KP_BLOCKS) {
        const size_t idx = ((size_t)bid * 256 + threadIdx.x) * 8;
        const float4 a = *reinterpret_cast<const float4*>(K + idx);
        const float4 c = *reinterpret_cast<const float4*>(K + idx + 4);
        float xs[8] = {a.x, a.y, a.z, a.w, c.x, c.y, c.z, c.w};
        half8 h8, l8;
#pragma unroll
        for (int i = 0; i < 8; ++i) {
            const _Float16 h = (_Float16)xs[i];
            h8[i] = h;
            l8[i] = (_Float16)(xs[i] - (float)h);
        }
        *reinterpret_cast<half8*>(Khi + idx) = h8;
        *reinterpret_cast<half8*>(Klo + idx) = l8;
    } else {
        const int t = (bid - KP_BLOCKS) * 256 + threadIdx.x;
        const int d = t & 63;
        const int s32 = (t >> 6) & (Ss / 32 - 1);
        const int b = t >> 13;
        const float* vp = V + ((size_t)b * Ss + (size_t)s32 * 32) * Dd + d;
        __align__(16) _Float16 ob[32];
#pragma unroll
        for (int j = 0; j < 32; ++j) ob[j] = (_Float16)vp[(size_t)j * Dd];
        _Float16* op = Vt + ((size_t)b * Dd + d) * Ss + (size_t)s32 * 32;
#pragma unroll
        for (int j8 = 0; j8 < 4; ++j8)
            *reinterpret_cast<half8*>(op + j8 * 8) = *reinterpret_cast<half8*>(ob + j8 * 8);
    }
}

union H8 { half8 h; unsigned int u[4]; };

// ------- main v12: v11 structure, launch_bounds fixed (2nd arg = BLOCKS/CU on hipcc) --
// 16 waves (1024 thr): wave w -> qg = w>>2 (64 q-rows of 256), p = w&3 (k-parity).
// Grid 256 blocks = exactly 1 block/CU; 16 waves/CU = 4/SIMD; VGPR cap 128 (need ~108).
// LDS 99KB: Khi 8 slots [0,32K) + Klo [32K,64K) + Vt [64K,96K) + merge ml [96K,99K).
__global__ __launch_bounds__(1024, 1)
void attn_fwd_v12(const float* __restrict__ Q, const float* __restrict__ inv_scale,
                  const _Float16* __restrict__ Khi, const _Float16* __restrict__ Klo,
                  const _Float16* __restrict__ Vt, float* __restrict__ Out)
{
    __shared__ __align__(16) unsigned char smem[99 * 1024];

    const int tid = threadIdx.x;
    const int lane = tid & 63;
    const int w = tid >> 6;
    const int p = w & 3;            // k-parity 0..3
    const int qg = w >> 2;          // 0..3, owns q-rows [qg*64, qg*64+64)
    const int l31 = lane & 31;
    const int hi = lane >> 5;

    // T1 XCD swizzle: 256 blocks -> each XCD owns 32 consecutive (2 batches)
    const int bid = (blockIdx.x & 7) * 32 + (blockIdx.x >> 3);
    const int b = bid >> 4;
    const int q0 = (bid & 15) * QBLK;

    const _Float16* KhB = Khi + (size_t)b * Ss * Dd;
    const _Float16* KlB = Klo + (size_t)b * Ss * Dd;
    const _Float16* VB = Vt + (size_t)b * Dd * Ss;

    // staging: 1024 threads stage a 4-tile group (one tile per 256-thread cohort).
    // linear LDS dest, swizzle pre-applied on GLOBAL source (rule #21).
    const int c = tid & 255;        // position within tile
    const int j4 = tid >> 8;        // which tile of the group (0..3)
    const int kk = c >> 3;
    const int ksrc = kk * Dd + (((c & 7) ^ (kk & 7)) << 3);
    const int dd_ = c >> 2;
    const size_t vsrc = (size_t)dd_ * Ss + (((c & 3) ^ ((dd_ >> 1) & 3)) << 3);

    // stage group g: tiles 4g..4g+3 into slots (4g+j)&7
#define STAGE4(g)                                                                           \
    do {                                                                                    \
        const int _t = 4 * (g) + j4;                                                        \
        const int _sl = _t & 7;                                                             \
        GLOAD_LDS16(KhB + (size_t)_t * (KBLK * Dd) + ksrc, smem + _sl * 4096 + c * 16);     \
        GLOAD_LDS16(KlB + (size_t)_t * (KBLK * Dd) + ksrc,                                  \
                    smem + 32768 + _sl * 4096 + c * 16);                                    \
        GLOAD_LDS16(VB + (size_t)_t * KBLK + vsrc, smem + 65536 + _sl * 4096 + c * 16);     \
    } while (0)

    STAGE4(0);

    // LDS read byte-offsets (swizzled), constant per thread
    int koff[4], voff[4];
#pragma unroll
    for (int ks = 0; ks < 4; ++ks)
        koff[ks] = l31 * 128 + ((((ks << 1) + hi) ^ (l31 & 7)) << 4);
#pragma unroll
    for (int i = 0; i < 4; ++i) {   // i = dblk*2 + ks ; conflict-free V swizzle (r7-verified)
        const int d = (i >> 1) * 32 + l31;
        voff[i] = d * 64 + (((((i & 1) << 1) + hi) ^ ((d >> 1) & 3)) << 4);
    }

    // Q fragments f16 hi/lo for 2 q-sub-blocks; lane: col q = l31, d = ks*16 + hi*8 ..+8
    H8 qhi[2][4], qlo[2][4];
    {
        const float s2 = (1.0f / inv_scale[0]) * kLOG2E;
#pragma unroll
        for (int qs = 0; qs < 2; ++qs) {
            const float* qrow = Q + ((size_t)b * Ss + q0 + qg * 64 + qs * 32 + l31) * Dd;
#pragma unroll
            for (int ks = 0; ks < 4; ++ks) {
                const int d0 = ks * 16 + hi * 8;
                const float4 a = *reinterpret_cast<const float4*>(qrow + d0);
                const float4 cc = *reinterpret_cast<const float4*>(qrow + d0 + 4);
                float xs[8] = {a.x, a.y, a.z, a.w, cc.x, cc.y, cc.z, cc.w};
#pragma unroll
                for (int i = 0; i < 8; ++i) {
                    const float x = xs[i] * s2;
                    const _Float16 h = (_Float16)x;
                    qhi[qs][ks].h[i] = h;
                    qlo[qs][ks].h[i] = (_Float16)(x - (float)h);
                }
            }
        }
    }

    f32x16 O0, O1, O2, O3;   // O0/O1: qs=0 dblk0/1 ; O2/O3: qs=1
#pragma unroll
    for (int r = 0; r < 16; ++r) { O0[r] = 0.f; O1[r] = 0.f; O2[r] = 0.f; O3[r] = 0.f; }
    float m0 = -INFINITY, l0 = 0.f, m1 = -INFINITY, l1 = 0.f;

    // v5-verified cross-half exchange (shfl-based)
    auto xhalf = [&](unsigned int& a, unsigned int& cx) {
        const unsigned int y = hi ? a : cx;
        const unsigned int sy = __shfl_xor(y, 32);
        const unsigned int na = hi ? sy : a;
        const unsigned int nc = hi ? cx : sy;
        a = na; cx = nc;
    };

    __syncthreads();   // group 0 resident (barrier drains vmcnt)

    for (int it = 0; it < NT / 4; ++it) {
        const int t = 4 * it + p;
        const unsigned char* khbase = smem + (t & 7) * 4096;
        const unsigned char* klbase = smem + 32768 + (t & 7) * 4096;
        const unsigned char* vbase = smem + 65536 + (t & 7) * 4096;

        if (it < NT / 4 - 1) STAGE4(it + 1);

        // ---- S^T = K·Q^T for BOTH q-sub-blocks: 8 K reads -> 24 MFMAs ----
        f32x16 S0, S1;
#pragma unroll
        for (int r = 0; r < 16; ++r) { S0[r] = 0.f; S1[r] = 0.f; }
        __builtin_amdgcn_s_setprio(1);
#pragma unroll
        for (int ks = 0; ks < 4; ++ks) {
            const half8 kh = *reinterpret_cast<const half8*>(khbase + koff[ks]);
            const half8 kl = *reinterpret_cast<const half8*>(klbase + koff[ks]);
            S0 = __builtin_amdgcn_mfma_f32_32x32x16_f16(kh, qhi[0][ks].h, S0, 0, 0, 0);
            S1 = __builtin_amdgcn_mfma_f32_32x32x16_f16(kh, qhi[1][ks].h, S1, 0, 0, 0);
            S0 = __builtin_amdgcn_mfma_f32_32x32x16_f16(kl, qhi[0][ks].h, S0, 0, 0, 0);
            S1 = __builtin_amdgcn_mfma_f32_32x32x16_f16(kl, qhi[1][ks].h, S1, 0, 0, 0);
            S0 = __builtin_amdgcn_mfma_f32_32x32x16_f16(kh, qlo[0][ks].h, S0, 0, 0, 0);
            S1 = __builtin_amdgcn_mfma_f32_32x32x16_f16(kh, qlo[1][ks].h, S1, 0, 0, 0);
        }
        __builtin_amdgcn_s_setprio(0);

        // ---- online softmax (log2 domain), defer-max, both chains ----
        float t0 = S0[0], t1 = S1[0];
#pragma unroll
        for (int r = 1; r < 16; ++r) { t0 = fmaxf(t0, S0[r]); t1 = fmaxf(t1, S1[r]); }
        t0 = fmaxf(t0, __shfl_xor(t0, 32));
        t1 = fmaxf(t1, __shfl_xor(t1, 32));

        float fac0 = 1.0f, fac1 = 1.0f;
        if (__any(fmaxf(t0 - m0, t1 - m1) > DEFER_THR)) {
            const float mn0 = fmaxf(m0, t0);
            fac0 = __builtin_amdgcn_exp2f(m0 - mn0);
            m0 = mn0;
            const float mn1 = fmaxf(m1, t1);
            fac1 = __builtin_amdgcn_exp2f(m1 - mn1);
            m1 = mn1;
#pragma unroll
            for (int r = 0; r < 16; ++r) {
                O0[r] *= fac0; O1[r] *= fac0;
                O2[r] *= fac1; O3[r] *= fac1;
            }
        }

        float ts0 = 0.f, ts1 = 0.f;
#pragma unroll
        for (int r = 0; r < 16; ++r) {
            S0[r] = __builtin_amdgcn_exp2f(S0[r] - m0);
            ts0 += S0[r];
            S1[r] = __builtin_amdgcn_exp2f(S1[r] - m1);
            ts1 += S1[r];
        }
        ts0 += __shfl_xor(ts0, 32);
        ts1 += __shfl_xor(ts1, 32);
        l0 = l0 * fac0 + ts0;
        l1 = l1 * fac1 + ts1;

        // ---- pack P to f16, cross-half exchange (v5-verified xhalf) ----
        unsigned int wa[8], wb[8];
#pragma unroll
        for (int j = 0; j < 8; ++j) {
            const auto ha = __builtin_amdgcn_cvt_pkrtz(S0[2 * j], S0[2 * j + 1]);
            wa[j] = __builtin_bit_cast(unsigned int, ha);
            const auto hb = __builtin_amdgcn_cvt_pkrtz(S1[2 * j], S1[2 * j + 1]);
            wb[j] = __builtin_bit_cast(unsigned int, hb);
        }
        xhalf(wa[0], wa[2]); xhalf(wa[1], wa[3]);
        xhalf(wa[4], wa[6]); xhalf(wa[5], wa[7]);
        xhalf(wb[0], wb[2]); xhalf(wb[1], wb[3]);
        xhalf(wb[4], wb[6]); xhalf(wb[5], wb[7]);

        H8 pa0, pa1, pb0, pb1;
        pa0.u[0] = wa[0]; pa0.u[1] = wa[1]; pa0.u[2] = wa[2]; pa0.u[3] = wa[3];
        pa1.u[0] = wa[4]; pa1.u[1] = wa[5]; pa1.u[2] = wa[6]; pa1.u[3] = wa[7];
        pb0.u[0] = wb[0]; pb0.u[1] = wb[1]; pb0.u[2] = wb[2]; pb0.u[3] = wb[3];
        pb1.u[0] = wb[4]; pb1.u[1] = wb[5]; pb1.u[2] = wb[6]; pb1.u[3] = wb[7];

        // ---- O^T += V^T · P : 4 V reads -> 8 MFMAs (V frags shared across qs) ----
        const half8 vf0 = *reinterpret_cast<const half8*>(vbase + voff[0]);
        const half8 vf1 = *reinterpret_cast<const half8*>(vbase + voff[1]);
        const half8 vf2 = *reinterpret_cast<const half8*>(vbase + voff[2]);
        const half8 vf3 = *reinterpret_cast<const half8*>(vbase + voff[3]);
        __builtin_amdgcn_s_setprio(1);
        O0 = __builtin_amdgcn_mfma_f32_32x32x16_f16(vf0, pa0.h, O0, 0, 0, 0);
        O2 = __builtin_amdgcn_mfma_f32_32x32x16_f16(vf0, pb0.h, O2, 0, 0, 0);
        O0 = __builtin_amdgcn_mfma_f32_32x32x16_f16(vf1, pa1.h, O0, 0, 0, 0);
        O2 = __builtin_amdgcn_mfma_f32_32x32x16_f16(vf1, pb1.h, O2, 0, 0, 0);
        O1 = __builtin_amdgcn_mfma_f32_32x32x16_f16(vf2, pa0.h, O1, 0, 0, 0);
        O3 = __builtin_amdgcn_mfma_f32_32x32x16_f16(vf2, pb0.h, O3, 0, 0, 0);
        O1 = __builtin_amdgcn_mfma_f32_32x32x16_f16(vf3, pa1.h, O1, 0, 0, 0);
        O3 = __builtin_amdgcn_mfma_f32_32x32x16_f16(vf3, pb1.h, O3, 0, 0, 0);
        __builtin_amdgcn_s_setprio(0);

        __syncthreads();   // staged group ready; slots free for reuse
    }

    // ---- merge 4 k-parities per (qg, qs): p=1,2,3 write partials; p=0 combines ----
    float* mO = (float*)smem;                  // 3 x [qg*2+dblk][rr][256] = 96KB
    float* ml = (float*)(smem + 96 * 1024);    // 3 x [qg][{m,l}][32] = 3KB

#define MERGE_ROUND(OA, OB, MV, LV, QS)                                                     \
    do {                                                                                    \
        if (p != 0) {                                                                       \
            const int pr = p - 1;                                                           \
            _Pragma("unroll") for (int rr = 0; rr < 4; ++rr) {                              \
                f32x4 va, vb;                                                               \
                _Pragma("unroll") for (int j = 0; j < 4; ++j) {                             \
                    va[j] = OA[rr * 4 + j];                                                 \
                    vb[j] = OB[rr * 4 + j];                                                 \
                }                                                                           \
                *reinterpret_cast<f32x4*>(                                                  \
                    mO + pr * 8192 + (((qg * 2 + 0) * 4 + rr) << 8) + lane * 4) = va;       \
                *reinterpret_cast<f32x4*>(                                                  \
                    mO + pr * 8192 + (((qg * 2 + 1) * 4 + rr) << 8) + lane * 4) = vb;       \
            }                                                                               \
            if (hi == 0) {                                                                  \
                ml[pr * 256 + qg * 64 + l31] = MV;                                          \
                ml[pr * 256 + qg * 64 + 32 + l31] = LV;                                     \
            }                                                                               \
        }                                                                                   \
        __syncthreads();                                                                    \
        if (p == 0) {                                                                       \
            float ms[3], ls[3];                                                             \
            float mm = MV;                                                                  \
            _Pragma("unroll") for (int i = 0; i < 3; ++i) {                                 \
                ms[i] = ml[i * 256 + qg * 64 + l31];                                        \
                ls[i] = ml[i * 256 + qg * 64 + 32 + l31];                                   \
                mm = fmaxf(mm, ms[i]);                                                      \
            }                                                                               \
            float f0 = __builtin_amdgcn_exp2f(MV - mm);                                     \
            float fi[3];                                                                    \
            float denom = LV * f0;                                                          \
            _Pragma("unroll") for (int i = 0; i < 3; ++i) {                                 \
                fi[i] = __builtin_amdgcn_exp2f(ms[i] - mm);                                 \
                denom += ls[i] * fi[i];                                                     \
            }                                                                               \
            const float inv = 1.0f / denom;                                                 \
            f0 *= inv;                                                                      \
            fi[0] *= inv; fi[1] *= inv; fi[2] *= inv;                                       \
            float* orow = Out + ((size_t)b * Ss + q0 + qg * 64 + (QS) * 32 + l31) * Dd;     \
            _Pragma("unroll") for (int dblk = 0; dblk < 2; ++dblk) {                        \
                _Pragma("unroll") for (int rr = 0; rr < 4; ++rr) {                          \
                    f32x4 res;                                                              \
                    _Pragma("unroll") for (int j = 0; j < 4; ++j)                           \
                        res[j] = ((dblk == 0) ? OA[rr * 4 + j] : OB[rr * 4 + j]) * f0;      \
                    _Pragma("unroll") for (int i = 0; i < 3; ++i) {                         \
                        const f32x4 ov = *reinterpret_cast<const f32x4*>(                   \
                            mO + i * 8192 + (((qg * 2 + dblk) * 4 + rr) << 8) + lane * 4);  \
                        _Pragma("unroll") for (int j = 0; j < 4; ++j)                       \
                            res[j] += ov[j] * fi[i];                                        \
                    }                                                                       \
                    *reinterpret_cast<f32x4*>(orow + dblk * 32 + rr * 8 + hi * 4) = res;    \
                }                                                                           \
            }                                                                               \
        }                                                                                   \
        __syncthreads();                                                                    \
    } while (0)

    MERGE_ROUND(O0, O1, m0, l0, 0);
    MERGE_ROUND(O2, O3, m1, l1, 1);
#undef MERGE_ROUND
#undef STAGE4
}

// ---------------- fallback (validated round-1 kernel) if workspace too small ---------
__global__ __launch_bounds__(256)
void attn_fwd_fallback(const float* __restrict__ Q, const float* __restrict__ K,
                       const float* __restrict__ V, const float* __restrict__ inv_scale,
                       float* __restrict__ Out)
{
    __shared__ __align__(16) ushort_t sKhi[KBLK * Dd];
    __shared__ __align__(16) ushort_t sKlo[KBLK * Dd];
    __shared__ __align__(16) ushort_t sVt[Dd * KBLK];
    __shared__ __align__(16) ushort_t sP[4][16 * KBLK];

    const int tid = threadIdx.x;
    const int lane = tid & 63;
    const int w = tid >> 6;
    const int q15 = lane & 15;
    const int g = lane >> 4;
    const int b = blockIdx.x >> 6;
    const int q0 = (blockIdx.x & 63) * 64;
    const float scale = 1.0f / inv_scale[0];

    const float* qptr = Q + (((size_t)b * Ss) + q0 + w * 16 + q15) * Dd;
    bf16x8 qhi[2], qlo[2];
#pragma unroll
    for (int ds = 0; ds < 2; ++ds) {
        const float4 f0 = *reinterpret_cast<const float4*>(qptr + ds * 32 + g * 8);
        const float4 f1 = *reinterpret_cast<const float4*>(qptr + ds * 32 + g * 8 + 4);
        float xs[8] = {f0.x, f0.y, f0.z, f0.w, f1.x, f1.y, f1.z, f1.w};
#pragma unroll
        for (int i = 0; i < 8; ++i) {
            __bf16 h = (__bf16)xs[i];
            qhi[ds][i] = h;
            qlo[ds][i] = (__bf16)(xs[i] - (float)h);
        }
    }
    const int krs = tid >> 3;
    const int kc8 = (tid & 7) * 8;
    const int kidx = krs * Dd + (kc8 ^ ((krs & 7) << 3));
    const float* kbase = K + ((size_t)b * Ss) * Dd;
    const int vd = tid & 63;
    const int vk8 = (tid >> 6) * 8;
    const int vidx = vd * KBLK + (vk8 ^ ((vd & 3) << 3));
    const float* vbase = V + ((size_t)b * Ss) * Dd;

    f32x4 Oacc[4];
#pragma unroll
    for (int dt = 0; dt < 4; ++dt)
#pragma unroll
        for (int r = 0; r < 4; ++r) Oacc[dt][r] = 0.f;
    float m_run = -INFINITY, l_run = 0.f;

    for (int k0 = 0; k0 < Ss; k0 += KBLK) {
        {
            const float* p0 = kbase + (size_t)(k0 + krs) * Dd + kc8;
            const float4 a = *reinterpret_cast<const float4*>(p0);
            const float4 c = *reinterpret_cast<const float4*>(p0 + 4);
            float xs[8] = {a.x, a.y, a.z, a.w, c.x, c.y, c.z, c.w};
            bf16x8 h8, l8;
#pragma unroll
            for (int i = 0; i < 8; ++i) {
                __bf16 h = (__bf16)xs[i];
                h8[i] = h;
                l8[i] = (__bf16)(xs[i] - (float)h);
            }
            *reinterpret_cast<bf16x8*>(&sKhi[kidx]) = h8;
            *reinterpret_cast<bf16x8*>(&sKlo[kidx]) = l8;
        }
        {
            bf16x8 v8;
#pragma unroll
            for (int j = 0; j < 8; ++j) v8[j] = (__bf16)vbase[(size_t)(k0 + vk8 + j) * Dd + vd];
            *reinterpret_cast<bf16x8*>(&sVt[vidx]) = v8;
        }
        __syncthreads();

        float z[2][4];
#pragma unroll
        for (int t = 0; t < 2; ++t) {
            const int krow = t * 16 + q15;
            f32x4 acc;
            acc[0] = acc[1] = acc[2] = acc[3] = 0.f;
#pragma unroll
            for (int ds = 0; ds < 2; ++ds) {
                const int ci = (ds * 32 + g * 8) ^ ((krow & 7) << 3);
                const bf16x8 kh = *reinterpret_cast<const bf16x8*>(&sKhi[krow * Dd + ci]);
                const bf16x8 kl = *reinterpret_cast<const bf16x8*>(&sKlo[krow * Dd + ci]);
                acc = __builtin_amdgcn_mfma_f32_16x16x32_bf16(kh, qhi[ds], acc, 0, 0, 0);
                acc = __builtin_amdgcn_mfma_f32_16x16x32_bf16(kl, qhi[ds], acc, 0, 0, 0);
                acc = __builtin_amdgcn_mfma_f32_16x16x32_bf16(kh, qlo[ds], acc, 0, 0, 0);
            }
#pragma unroll
            for (int r = 0; r < 4; ++r) z[t][r] = acc[r] * scale;
        }

        float tmax = z[0][0];
#pragma unroll
        for (int t = 0; t < 2; ++t)
#pragma unroll
            for (int r = 0; r < 4; ++r) tmax = fmaxf(tmax, z[t][r]);
        tmax = fmaxf(tmax, __shfl_xor(tmax, 16));
        tmax = fmaxf(tmax, __shfl_xor(tmax, 32));
        const float m_new = fmaxf(m_run, tmax);

        float pz[2][4];
        float tsum = 0.f;
#pragma unroll
        for (int t = 0; t < 2; ++t)
#pragma unroll
            for (int r = 0; r < 4; ++r) {
                const float e = __builtin_amdgcn_exp2f((z[t][r] - m_new) * kLOG2E);
                pz[t][r] = e;
                tsum += e;
            }
        tsum += __shfl_xor(tsum, 16);
        tsum += __shfl_xor(tsum, 32);
        const float fac = __builtin_amdgcn_exp2f((m_run - m_new) * kLOG2E);
        l_run = l_run * fac + tsum;
        m_run = m_new;

#pragma unroll
        for (int t = 0; t < 2; ++t) {
            bf16x4 pb;
#pragma unroll
            for (int r = 0; r < 4; ++r) pb[r] = (__bf16)pz[t][r];
            const int pidx = q15 * KBLK + ((t * 16 + g * 4) ^ ((q15 & 3) << 3));
            *reinterpret_cast<bf16x4*>(&sP[w][pidx]) = pb;
        }
        {
            const float fr0 = __shfl(fac, g * 4 + 0);
            const float fr1 = __shfl(fac, g * 4 + 1);
            const float fr2 = __shfl(fac, g * 4 + 2);
            const float fr3 = __shfl(fac, g * 4 + 3);
#pragma unroll
            for (int dt = 0; dt < 4; ++dt) {
                Oacc[dt][0] *= fr0; Oacc[dt][1] *= fr1;
                Oacc[dt][2] *= fr2; Oacc[dt][3] *= fr3;
            }
        }
        const int paidx = q15 * KBLK + ((g * 8) ^ ((q15 & 3) << 3));
        const bf16x8 pa = *reinterpret_cast<const bf16x8*>(&sP[w][paidx]);
#pragma unroll
        for (int dt = 0; dt < 4; ++dt) {
            const int dd = dt * 16 + q15;
            const bf16x8 vf =
                *reinterpret_cast<const bf16x8*>(&sVt[dd * KBLK + ((g * 8) ^ ((dd & 3) << 3))]);
            Oacc[dt] = __builtin_amdgcn_mfma_f32_16x16x32_bf16(pa, vf, Oacc[dt], 0, 0, 0);
        }
        __syncthreads();
    }

    const float invl = 1.0f / l_run;
    float il[4];
#pragma unroll
    for (int r = 0; r < 4; ++r) il[r] = __shfl(invl, g * 4 + r);
    float* obase = Out + (((size_t)b * Ss) + q0 + w * 16) * Dd;
#pragma unroll
    for (int dt = 0; dt < 4; ++dt)
#pragma unroll
        for (int r = 0; r < 4; ++r)
            obase[(size_t)(g * 4 + r) * Dd + dt * 16 + q15] = Oacc[dt][r] * il[r];
}

extern "C" void kernel_launch(void* const* d_in, const int* in_sizes, int n_in,
                              void* d_out, int out_size, void* d_ws, size_t ws_size,
                              hipStream_t stream)
{
    const float* q = (const float*)d_in[0];
    const float* k = (const float*)d_in[1];
    const float* v = (const float*)d_in[2];
    const float* inv_scale = (const float*)d_in[3];
    float* out = (float*)d_out;
    (void)in_sizes; (void)n_in; (void)out_size;

    const size_t NKV = (size_t)Bb * Ss * Dd;                 // elements per K/V tensor
    const size_t need = NKV * 3 * sizeof(_Float16);          // Khi + Klo + Vt

    if (ws_size >= need) {
        _Float16* Khi = (_Float16*)d_ws;
        _Float16* Klo = Khi + NKV;
        _Float16* Vt = Klo + NKV;
        hipLaunchKernelGGL(prep_f16s, dim3(KP_BLOCKS + VT_BLOCKS), dim3(256), 0, stream,
                           k, v, Khi, Klo, Vt);
        hipLaunchKernelGGL(attn_fwd_v12, dim3(Bb * (Ss / QBLK)), dim3(1024), 0, stream,
                           q, inv_scale, Khi, Klo, Vt, out);
    } else {
        hipLaunchKernelGGL(attn_fwd_fallback, dim3(Bb * 64), dim3(256), 0, stream,
                           q, k, v, inv_scale, out);
    }
}

// Round 13
// 175.492 us; speedup vs baseline: 2.3599x; 2.3599x over previous
//
#include <hip/hip_runtime.h>
#include <hip/hip_bf16.h>

typedef float f32x4 __attribute__((ext_vector_type(4)));
typedef float f32x16 __attribute__((ext_vector_type(16)));
typedef _Float16 half8 __attribute__((ext_vector_type(8)));
typedef __bf16 bf16x8 __attribute__((ext_vector_type(8)));
typedef __bf16 bf16x4 __attribute__((ext_vector_type(4)));
typedef unsigned short ushort_t;

constexpr int Bb = 16, Ss = 4096, Dd = 64;
constexpr int KBLK = 32, QBLK = 128;
constexpr int NT = Ss / KBLK;   // 128 tiles, 4 parities -> 32 iterations
constexpr int NITER = NT / 4;
constexpr float kLOG2E = 1.44269504088896340736f;
constexpr float DEFER_THR = 10.0f;   // exp2(10)=1024 max P; fp16-safe

constexpr int KP_BLOCKS = (Bb * Ss * Dd / 8) / 256;      // 2048
constexpr int VT_BLOCKS = (Bb * Dd * (Ss / 32)) / 256;   // 512

#define GLOAD_LDS16(gp, lp)                                                              \
    __builtin_amdgcn_global_load_lds(                                                    \
        (const __attribute__((address_space(1))) void*)(gp),                             \
        (__attribute__((address_space(3))) void*)(lp), 16, 0, 0)

// ------- pre-pass: K -> f16 hi/lo [b][s][d]; V -> Vt f16 [b][d][s] (round-6 verified) -
__global__ __launch_bounds__(256)
void prep_f16s(const float* __restrict__ K, const float* __restrict__ V,
               _Float16* __restrict__ Khi, _Float16* __restrict__ Klo,
               _Float16* __restrict__ Vt)
{
    const int bid = blockIdx.x;
    if (bid < KP_BLOCKS) {
        const size_t idx = ((size_t)bid * 256 + threadIdx.x) * 8;
        const float4 a = *reinterpret_cast<const float4*>(K + idx);
        const float4 c = *reinterpret_cast<const float4*>(K + idx + 4);
        float xs[8] = {a.x, a.y, a.z, a.w, c.x, c.y, c.z, c.w};
        half8 h8, l8;
#pragma unroll
        for (int i = 0; i < 8; ++i) {
            const _Float16 h = (_Float16)xs[i];
            h8[i] = h;
            l8[i] = (_Float16)(xs[i] - (float)h);
        }
        *reinterpret_cast<half8*>(Khi + idx) = h8;
        *reinterpret_cast<half8*>(Klo + idx) = l8;
    } else {
        const int t = (bid - KP_BLOCKS) * 256 + threadIdx.x;
        const int d = t & 63;
        const int s32 = (t >> 6) & (Ss / 32 - 1);
        const int b = t >> 13;
        const float* vp = V + ((size_t)b * Ss + (size_t)s32 * 32) * Dd + d;
        __align__(16) _Float16 ob[32];
#pragma unroll
        for (int j = 0; j < 32; ++j) ob[j] = (_Float16)vp[(size_t)j * Dd];
        _Float16* op = Vt + ((size_t)b * Dd + d) * Ss + (size_t)s32 * 32;
#pragma unroll
        for (int j8 = 0; j8 < 4; ++j8)
            *reinterpret_cast<half8*>(op + j8 * 8) = *reinterpret_cast<half8*>(ob + j8 * 8);
    }
}

union H8 { half8 h; unsigned int u[4]; };

// ------- main v13: 3-pass split-fp16 QK, 64 q-rows/wave, 4-way k-split, 512 thr ------
// 8 waves: wave w -> qg = w>>2 (64 q-rows of 128), p = w&3 (k-parity).
// Grid 512 blocks = 2 blocks/CU -> 16 waves/CU = 4/SIMD. VGPR ~108 (v10-measured core).
// LDS 80KB: Khi 8-slot ring [0,32K) + Klo [32K,64K) (double-buffered; QK needs K at
// barrier) + Vt 4 slots [64K,80K) (single-buffered; staged at iter start, consumed
// after QK+softmax; readiness via s_waitcnt vmcnt(4) leaving K-prefetch in flight).
__global__ __launch_bounds__(512, 2)
void attn_fwd_v13(const float* __restrict__ Q, const float* __restrict__ inv_scale,
                  const _Float16* __restrict__ Khi, const _Float16* __restrict__ Klo,
                  const _Float16* __restrict__ Vt, float* __restrict__ Out)
{
    __shared__ __align__(16) unsigned char smem[80 * 1024];

    const int tid = threadIdx.x;
    const int lane = tid & 63;
    const int w = tid >> 6;
    const int p = w & 3;            // k-parity 0..3
    const int qg = w >> 2;          // 0..1, owns q-rows [qg*64, qg*64+64)
    const int l31 = lane & 31;
    const int hi = lane >> 5;

    // T1 XCD swizzle: 512 blocks -> each XCD owns 64 consecutive (2 batches)
    const int bid = (blockIdx.x & 7) * 64 + (blockIdx.x >> 3);
    const int b = bid >> 5;
    const int q0 = (bid & 31) * QBLK;

    const _Float16* KhB = Khi + (size_t)b * Ss * Dd;
    const _Float16* KlB = Klo + (size_t)b * Ss * Dd;
    const _Float16* VB = Vt + (size_t)b * Dd * Ss;

    // staging: 512 threads, thread -> (tile j4 = tid>>7, 2 positions c2, c2+128).
    // linear LDS dest, swizzle pre-applied on GLOBAL source (rule #21).
    const int c2 = tid & 127;
    const int j4 = tid >> 7;        // which tile of the 4-tile group

    // K group g: tiles 4g+j4 -> slots (4g+j4)&7 (8-ring). 4 gloads/thread.
#define STAGE_K(g)                                                                          \
    do {                                                                                    \
        const int _t = 4 * (g) + j4;                                                        \
        const int _sl = _t & 7;                                                             \
        _Pragma("unroll") for (int _r = 0; _r < 2; ++_r) {                                  \
            const int _q = c2 + _r * 128;                                                   \
            const int _kk = _q >> 3;                                                        \
            const int _off = _kk * Dd + (((_q & 7) ^ (_kk & 7)) << 3);                      \
            GLOAD_LDS16(KhB + (size_t)_t * (KBLK * Dd) + _off,                              \
                        smem + _sl * 4096 + _q * 16);                                       \
            GLOAD_LDS16(KlB + (size_t)_t * (KBLK * Dd) + _off,                              \
                        smem + 32768 + _sl * 4096 + _q * 16);                               \
        }                                                                                   \
    } while (0)

    // V group g: tiles 4g+j4 -> slot j4 (4 slots). 2 gloads/thread. Conflict-free swizzle.
#define STAGE_V(g)                                                                          \
    do {                                                                                    \
        const int _t = 4 * (g) + j4;                                                        \
        _Pragma("unroll") for (int _r = 0; _r < 2; ++_r) {                                  \
            const int _q = c2 + _r * 128;                                                   \
            const int _dd = _q >> 2;                                                        \
            const size_t _off =                                                             \
                (size_t)_dd * Ss + (((_q & 3) ^ ((_dd >> 1) & 3)) << 3);                    \
            GLOAD_LDS16(VB + (size_t)_t * KBLK + _off,                                      \
                        smem + 65536 + j4 * 4096 + _q * 16);                                \
        }                                                                                   \
    } while (0)

    STAGE_K(0);

    // LDS read byte-offsets (swizzled), constant per thread
    int koff[4], voff[4];
#pragma unroll
    for (int ks = 0; ks < 4; ++ks)
        koff[ks] = l31 * 128 + ((((ks << 1) + hi) ^ (l31 & 7)) << 4);
#pragma unroll
    for (int i = 0; i < 4; ++i) {   // i = dblk*2 + ks ; conflict-free V swizzle (r7-verified)
        const int d = (i >> 1) * 32 + l31;
        voff[i] = d * 64 + (((((i & 1) << 1) + hi) ^ ((d >> 1) & 3)) << 4);
    }

    // Q fragments f16 hi/lo for 2 q-sub-blocks; lane: col q = l31, d = ks*16 + hi*8 ..+8
    H8 qhi[2][4], qlo[2][4];
    {
        const float s2 = (1.0f / inv_scale[0]) * kLOG2E;
#pragma unroll
        for (int qs = 0; qs < 2; ++qs) {
            const float* qrow = Q + ((size_t)b * Ss + q0 + qg * 64 + qs * 32 + l31) * Dd;
#pragma unroll
            for (int ks = 0; ks < 4; ++ks) {
                const int d0 = ks * 16 + hi * 8;
                const float4 a = *reinterpret_cast<const float4*>(qrow + d0);
                const float4 cc = *reinterpret_cast<const float4*>(qrow + d0 + 4);
                float xs[8] = {a.x, a.y, a.z, a.w, cc.x, cc.y, cc.z, cc.w};
#pragma unroll
                for (int i = 0; i < 8; ++i) {
                    const float x = xs[i] * s2;
                    const _Float16 h = (_Float16)x;
                    qhi[qs][ks].h[i] = h;
                    qlo[qs][ks].h[i] = (_Float16)(x - (float)h);
                }
            }
        }
    }

    f32x16 O0, O1, O2, O3;   // O0/O1: qs=0 dblk0/1 ; O2/O3: qs=1
#pragma unroll
    for (int r = 0; r < 16; ++r) { O0[r] = 0.f; O1[r] = 0.f; O2[r] = 0.f; O3[r] = 0.f; }
    float m0 = -INFINITY, l0 = 0.f, m1 = -INFINITY, l1 = 0.f;

    // v5-verified cross-half exchange (shfl-based)
    auto xhalf = [&](unsigned int& a, unsigned int& cx) {
        const unsigned int y = hi ? a : cx;
        const unsigned int sy = __shfl_xor(y, 32);
        const unsigned int na = hi ? sy : a;
        const unsigned int nc = hi ? cx : sy;
        a = na; cx = nc;
    };

    __syncthreads();   // K group 0 resident (barrier drains vmcnt)

    for (int it = 0; it < NITER; ++it) {
        const int t = 4 * it + p;
        const unsigned char* khbase = smem + (t & 7) * 4096;
        const unsigned char* klbase = smem + 32768 + (t & 7) * 4096;
        const unsigned char* vbase = smem + 65536 + p * 4096;   // V slot = parity

        STAGE_V(it);                        // 2 gloads (oldest)
        if (it < NITER - 1) STAGE_K(it + 1); // 4 gloads (stay in flight past vmcnt(4))

        // ---- S^T = K·Q^T for BOTH q-sub-blocks: 8 K reads -> 24 MFMAs ----
        f32x16 S0, S1;
#pragma unroll
        for (int r = 0; r < 16; ++r) { S0[r] = 0.f; S1[r] = 0.f; }
        __builtin_amdgcn_s_setprio(1);
#pragma unroll
        for (int ks = 0; ks < 4; ++ks) {
            const half8 kh = *reinterpret_cast<const half8*>(khbase + koff[ks]);
            const half8 kl = *reinterpret_cast<const half8*>(klbase + koff[ks]);
            S0 = __builtin_amdgcn_mfma_f32_32x32x16_f16(kh, qhi[0][ks].h, S0, 0, 0, 0);
            S1 = __builtin_amdgcn_mfma_f32_32x32x16_f16(kh, qhi[1][ks].h, S1, 0, 0, 0);
            S0 = __builtin_amdgcn_mfma_f32_32x32x16_f16(kl, qhi[0][ks].h, S0, 0, 0, 0);
            S1 = __builtin_amdgcn_mfma_f32_32x32x16_f16(kl, qhi[1][ks].h, S1, 0, 0, 0);
            S0 = __builtin_amdgcn_mfma_f32_32x32x16_f16(kh, qlo[0][ks].h, S0, 0, 0, 0);
            S1 = __builtin_amdgcn_mfma_f32_32x32x16_f16(kh, qlo[1][ks].h, S1, 0, 0, 0);
        }
        __builtin_amdgcn_s_setprio(0);

        // ---- online softmax (log2 domain), defer-max, both chains ----
        float t0 = S0[0], t1 = S1[0];
#pragma unroll
        for (int r = 1; r < 16; ++r) { t0 = fmaxf(t0, S0[r]); t1 = fmaxf(t1, S1[r]); }
        t0 = fmaxf(t0, __shfl_xor(t0, 32));
        t1 = fmaxf(t1, __shfl_xor(t1, 32));

        float fac0 = 1.0f, fac1 = 1.0f;
        if (__any(fmaxf(t0 - m0, t1 - m1) > DEFER_THR)) {
            const float mn0 = fmaxf(m0, t0);
            fac0 = __builtin_amdgcn_exp2f(m0 - mn0);
            m0 = mn0;
            const float mn1 = fmaxf(m1, t1);
            fac1 = __builtin_amdgcn_exp2f(m1 - mn1);
            m1 = mn1;
#pragma unroll
            for (int r = 0; r < 16; ++r) {
                O0[r] *= fac0; O1[r] *= fac0;
                O2[r] *= fac1; O3[r] *= fac1;
            }
        }

        float ts0 = 0.f, ts1 = 0.f;
#pragma unroll
        for (int r = 0; r < 16; ++r) {
            S0[r] = __builtin_amdgcn_exp2f(S0[r] - m0);
            ts0 += S0[r];
            S1[r] = __builtin_amdgcn_exp2f(S1[r] - m1);
            ts1 += S1[r];
        }
        ts0 += __shfl_xor(ts0, 32);
        ts1 += __shfl_xor(ts1, 32);
        l0 = l0 * fac0 + ts0;
        l1 = l1 * fac1 + ts1;

        // ---- drain the V stage (2 oldest vmem); K prefetch stays in flight ----
        if (it < NITER - 1)
            asm volatile("s_waitcnt vmcnt(4)" ::: "memory");
        else
            asm volatile("s_waitcnt vmcnt(0)" ::: "memory");
        __builtin_amdgcn_sched_barrier(0);

        // ---- pack P to f16, cross-half exchange (v5-verified xhalf) ----
        unsigned int wa[8], wb[8];
#pragma unroll
        for (int j = 0; j < 8; ++j) {
            const auto ha = __builtin_amdgcn_cvt_pkrtz(S0[2 * j], S0[2 * j + 1]);
            wa[j] = __builtin_bit_cast(unsigned int, ha);
            const auto hb = __builtin_amdgcn_cvt_pkrtz(S1[2 * j], S1[2 * j + 1]);
            wb[j] = __builtin_bit_cast(unsigned int, hb);
        }
        xhalf(wa[0], wa[2]); xhalf(wa[1], wa[3]);
        xhalf(wa[4], wa[6]); xhalf(wa[5], wa[7]);
        xhalf(wb[0], wb[2]); xhalf(wb[1], wb[3]);
        xhalf(wb[4], wb[6]); xhalf(wb[5], wb[7]);

        H8 pa0, pa1, pb0, pb1;
        pa0.u[0] = wa[0]; pa0.u[1] = wa[1]; pa0.u[2] = wa[2]; pa0.u[3] = wa[3];
        pa1.u[0] = wa[4]; pa1.u[1] = wa[5]; pa1.u[2] = wa[6]; pa1.u[3] = wa[7];
        pb0.u[0] = wb[0]; pb0.u[1] = wb[1]; pb0.u[2] = wb[2]; pb0.u[3] = wb[3];
        pb1.u[0] = wb[4]; pb1.u[1] = wb[5]; pb1.u[2] = wb[6]; pb1.u[3] = wb[7];

        // ---- O^T += V^T · P : 4 V reads -> 8 MFMAs (V frags shared across qs) ----
        const half8 vf0 = *reinterpret_cast<const half8*>(vbase + voff[0]);
        const half8 vf1 = *reinterpret_cast<const half8*>(vbase + voff[1]);
        const half8 vf2 = *reinterpret_cast<const half8*>(vbase + voff[2]);
        const half8 vf3 = *reinterpret_cast<const half8*>(vbase + voff[3]);
        __builtin_amdgcn_s_setprio(1);
        O0 = __builtin_amdgcn_mfma_f32_32x32x16_f16(vf0, pa0.h, O0, 0, 0, 0);
        O2 = __builtin_amdgcn_mfma_f32_32x32x16_f16(vf0, pb0.h, O2, 0, 0, 0);
        O0 = __builtin_amdgcn_mfma_f32_32x32x16_f16(vf1, pa1.h, O0, 0, 0, 0);
        O2 = __builtin_amdgcn_mfma_f32_32x32x16_f16(vf1, pb1.h, O2, 0, 0, 0);
        O1 = __builtin_amdgcn_mfma_f32_32x32x16_f16(vf2, pa0.h, O1, 0, 0, 0);
        O3 = __builtin_amdgcn_mfma_f32_32x32x16_f16(vf2, pb0.h, O3, 0, 0, 0);
        O1 = __builtin_amdgcn_mfma_f32_32x32x16_f16(vf3, pa1.h, O1, 0, 0, 0);
        O3 = __builtin_amdgcn_mfma_f32_32x32x16_f16(vf3, pb1.h, O3, 0, 0, 0);
        __builtin_amdgcn_s_setprio(0);

        __syncthreads();   // K group it+1 resident; V slots free for next iteration
    }

    // ---- merge 4 k-parities per (qg, qs): p=1,2,3 write partials; p=0 combines ----
    float* mO = (float*)smem;                  // 3 x 4096 floats = 48KB overlay
    float* ml = (float*)(smem + 48 * 1024);    // 3 x 128 floats

#define MERGE_ROUND(OA, OB, MV, LV, QS)                                                     \
    do {                                                                                    \
        if (p != 0) {                                                                       \
            const int pr = p - 1;                                                           \
            _Pragma("unroll") for (int rr = 0; rr < 4; ++rr) {                              \
                f32x4 va, vb;                                                               \
                _Pragma("unroll") for (int j = 0; j < 4; ++j) {                             \
                    va[j] = OA[rr * 4 + j];                                                 \
                    vb[j] = OB[rr * 4 + j];                                                 \
                }                                                                           \
                *reinterpret_cast<f32x4*>(                                                  \
                    mO + pr * 4096 + (((qg * 2 + 0) * 4 + rr) << 8) + lane * 4) = va;       \
                *reinterpret_cast<f32x4*>(                                                  \
                    mO + pr * 4096 + (((qg * 2 + 1) * 4 + rr) << 8) + lane * 4) = vb;       \
            }                                                                               \
            if (hi == 0) {                                                                  \
                ml[pr * 128 + qg * 64 + l31] = MV;                                          \
                ml[pr * 128 + qg * 64 + 32 + l31] = LV;                                     \
            }                                                                               \
        }                                                                                   \
        __syncthreads();                                                                    \
        if (p == 0) {                                                                       \
            float ms[3], ls[3];                                                             \
            float mm = MV;                                                                  \
            _Pragma("unroll") for (int i = 0; i < 3; ++i) {                                 \
                ms[i] = ml[i * 128 + qg * 64 + l31];                                        \
                ls[i] = ml[i * 128 + qg * 64 + 32 + l31];                                   \
                mm = fmaxf(mm, ms[i]);                                                      \
            }                                                                               \
            float f0 = __builtin_amdgcn_exp2f(MV - mm);                                     \
            float fi[3];                                                                    \
            float denom = LV * f0;                                                          \
            _Pragma("unroll") for (int i = 0; i < 3; ++i) {                                 \
                fi[i] = __builtin_amdgcn_exp2f(ms[i] - mm);                                 \
                denom += ls[i] * fi[i];                                                     \
            }                                                                               \
            const float inv = 1.0f / denom;                                                 \
            f0 *= inv;                                                                      \
            fi[0] *= inv; fi[1] *= inv; fi[2] *= inv;                                       \
            float* orow = Out + ((size_t)b * Ss + q0 + qg * 64 + (QS) * 32 + l31) * Dd;     \
            _Pragma("unroll") for (int dblk = 0; dblk < 2; ++dblk) {                        \
                _Pragma("unroll") for (int rr = 0; rr < 4; ++rr) {                          \
                    f32x4 res;                                                              \
                    _Pragma("unroll") for (int j = 0; j < 4; ++j)                           \
                        res[j] = ((dblk == 0) ? OA[rr * 4 + j] : OB[rr * 4 + j]) * f0;      \
                    _Pragma("unroll") for (int i = 0; i < 3; ++i) {                         \
                        const f32x4 ov = *reinterpret_cast<const f32x4*>(                   \
                            mO + i * 4096 + (((qg * 2 + dblk) * 4 + rr) << 8) + lane * 4);  \
                        _Pragma("unroll") for (int j = 0; j < 4; ++j)                       \
                            res[j] += ov[j] * fi[i];                                        \
                    }                                                                       \
                    *reinterpret_cast<f32x4*>(orow + dblk * 32 + rr * 8 + hi * 4) = res;    \
                }                                                                           \
            }                                                                               \
        }                                                                                   \
        __syncthreads();                                                                    \
    } while (0)

    MERGE_ROUND(O0, O1, m0, l0, 0);
    MERGE_ROUND(O2, O3, m1, l1, 1);
#undef MERGE_ROUND
#undef STAGE_K
#undef STAGE_V
}

// ---------------- fallback (validated round-1 kernel) if workspace too small ---------
__global__ __launch_bounds__(256)
void attn_fwd_fallback(const float* __restrict__ Q, const float* __restrict__ K,
                       const float* __restrict__ V, const float* __restrict__ inv_scale,
                       float* __restrict__ Out)
{
    __shared__ __align__(16) ushort_t sKhi[KBLK * Dd];
    __shared__ __align__(16) ushort_t sKlo[KBLK * Dd];
    __shared__ __align__(16) ushort_t sVt[Dd * KBLK];
    __shared__ __align__(16) ushort_t sP[4][16 * KBLK];

    const int tid = threadIdx.x;
    const int lane = tid & 63;
    const int w = tid >> 6;
    const int q15 = lane & 15;
    const int g = lane >> 4;
    const int b = blockIdx.x >> 6;
    const int q0 = (blockIdx.x & 63) * 64;
    const float scale = 1.0f / inv_scale[0];

    const float* qptr = Q + (((size_t)b * Ss) + q0 + w * 16 + q15) * Dd;
    bf16x8 qhi[2], qlo[2];
#pragma unroll
    for (int ds = 0; ds < 2; ++ds) {
        const float4 f0 = *reinterpret_cast<const float4*>(qptr + ds * 32 + g * 8);
        const float4 f1 = *reinterpret_cast<const float4*>(qptr + ds * 32 + g * 8 + 4);
        float xs[8] = {f0.x, f0.y, f0.z, f0.w, f1.x, f1.y, f1.z, f1.w};
#pragma unroll
        for (int i = 0; i < 8; ++i) {
            __bf16 h = (__bf16)xs[i];
            qhi[ds][i] = h;
            qlo[ds][i] = (__bf16)(xs[i] - (float)h);
        }
    }
    const int krs = tid >> 3;
    const int kc8 = (tid & 7) * 8;
    const int kidx = krs * Dd + (kc8 ^ ((krs & 7) << 3));
    const float* kbase = K + ((size_t)b * Ss) * Dd;
    const int vd = tid & 63;
    const int vk8 = (tid >> 6) * 8;
    const int vidx = vd * KBLK + (vk8 ^ ((vd & 3) << 3));
    const float* vbase = V + ((size_t)b * Ss) * Dd;

    f32x4 Oacc[4];
#pragma unroll
    for (int dt = 0; dt < 4; ++dt)
#pragma unroll
        for (int r = 0; r < 4; ++r) Oacc[dt][r] = 0.f;
    float m_run = -INFINITY, l_run = 0.f;

    for (int k0 = 0; k0 < Ss; k0 += KBLK) {
        {
            const float* p0 = kbase + (size_t)(k0 + krs) * Dd + kc8;
            const float4 a = *reinterpret_cast<const float4*>(p0);
            const float4 c = *reinterpret_cast<const float4*>(p0 + 4);
            float xs[8] = {a.x, a.y, a.z, a.w, c.x, c.y, c.z, c.w};
            bf16x8 h8, l8;
#pragma unroll
            for (int i = 0; i < 8; ++i) {
                __bf16 h = (__bf16)xs[i];
                h8[i] = h;
                l8[i] = (__bf16)(xs[i] - (float)h);
            }
            *reinterpret_cast<bf16x8*>(&sKhi[kidx]) = h8;
            *reinterpret_cast<bf16x8*>(&sKlo[kidx]) = l8;
        }
        {
            bf16x8 v8;
#pragma unroll
            for (int j = 0; j < 8; ++j) v8[j] = (__bf16)vbase[(size_t)(k0 + vk8 + j) * Dd + vd];
            *reinterpret_cast<bf16x8*>(&sVt[vidx]) = v8;
        }
        __syncthreads();

        float z[2][4];
#pragma unroll
        for (int t = 0; t < 2; ++t) {
            const int krow = t * 16 + q15;
            f32x4 acc;
            acc[0] = acc[1] = acc[2] = acc[3] = 0.f;
#pragma unroll
            for (int ds = 0; ds < 2; ++ds) {
                const int ci = (ds * 32 + g * 8) ^ ((krow & 7) << 3);
                const bf16x8 kh = *reinterpret_cast<const bf16x8*>(&sKhi[krow * Dd + ci]);
                const bf16x8 kl = *reinterpret_cast<const bf16x8*>(&sKlo[krow * Dd + ci]);
                acc = __builtin_amdgcn_mfma_f32_16x16x32_bf16(kh, qhi[ds], acc, 0, 0, 0);
                acc = __builtin_amdgcn_mfma_f32_16x16x32_bf16(kl, qhi[ds], acc, 0, 0, 0);
                acc = __builtin_amdgcn_mfma_f32_16x16x32_bf16(kh, qlo[ds], acc, 0, 0, 0);
            }
#pragma unroll
            for (int r = 0; r < 4; ++r) z[t][r] = acc[r] * scale;
        }

        float tmax = z[0][0];
#pragma unroll
        for (int t = 0; t < 2; ++t)
#pragma unroll
            for (int r = 0; r < 4; ++r) tmax = fmaxf(tmax, z[t][r]);
        tmax = fmaxf(tmax, __shfl_xor(tmax, 16));
        tmax = fmaxf(tmax, __shfl_xor(tmax, 32));
        const float m_new = fmaxf(m_run, tmax);

        float pz[2][4];
        float tsum = 0.f;
#pragma unroll
        for (int t = 0; t < 2; ++t)
#pragma unroll
            for (int r = 0; r < 4; ++r) {
                const float e = __builtin_amdgcn_exp2f((z[t][r] - m_new) * kLOG2E);
                pz[t][r] = e;
                tsum += e;
            }
        tsum += __shfl_xor(tsum, 16);
        tsum += __shfl_xor(tsum, 32);
        const float fac = __builtin_amdgcn_exp2f((m_run - m_new) * kLOG2E);
        l_run = l_run * fac + tsum;
        m_run = m_new;

#pragma unroll
        for (int t = 0; t < 2; ++t) {
            bf16x4 pb;
#pragma unroll
            for (int r = 0; r < 4; ++r) pb[r] = (__bf16)pz[t][r];
            const int pidx = q15 * KBLK + ((t * 16 + g * 4) ^ ((q15 & 3) << 3));
            *reinterpret_cast<bf16x4*>(&sP[w][pidx]) = pb;
        }
        {
            const float fr0 = __shfl(fac, g * 4 + 0);
            const float fr1 = __shfl(fac, g * 4 + 1);
            const float fr2 = __shfl(fac, g * 4 + 2);
            const float fr3 = __shfl(fac, g * 4 + 3);
#pragma unroll
            for (int dt = 0; dt < 4; ++dt) {
                Oacc[dt][0] *= fr0; Oacc[dt][1] *= fr1;
                Oacc[dt][2] *= fr2; Oacc[dt][3] *= fr3;
            }
        }
        const int paidx = q15 * KBLK + ((g * 8) ^ ((q15 & 3) << 3));
        const bf16x8 pa = *reinterpret_cast<const bf16x8*>(&sP[w][paidx]);
#pragma unroll
        for (int dt = 0; dt < 4; ++dt) {
            const int dd = dt * 16 + q15;
            const bf16x8 vf =
                *reinterpret_cast<const bf16x8*>(&sVt[dd * KBLK + ((g * 8) ^ ((dd & 3) << 3))]);
            Oacc[dt] = __builtin_amdgcn_mfma_f32_16x16x32_bf16(pa, vf, Oacc[dt], 0, 0, 0);
        }
        __syncthreads();
    }

    const float invl = 1.0f / l_run;
    float il[4];
#pragma unroll
    for (int r = 0; r < 4; ++r) il[r] = __shfl(invl, g * 4 + r);
    float* obase = Out + (((size_t)b * Ss) + q0 + w * 16) * Dd;
#pragma unroll
    for (int dt = 0; dt < 4; ++dt)
#pragma unroll
        for (int r = 0; r < 4; ++r)
            obase[(size_t)(g * 4 + r) * Dd + dt * 16 + q15] = Oacc[dt][r] * il[r];
}

extern "C" void kernel_launch(void* const* d_in, const int* in_sizes, int n_in,
                              void* d_out, int out_size, void* d_ws, size_t ws_size,
                              hipStream_t stream)
{
    const float* q = (const float*)d_in[0];
    const float* k = (const float*)d_in[1];
    const float* v = (const float*)d_in[2];
    const float* inv_scale = (const float*)d_in[3];
    float* out = (float*)d_out;
    (void)in_sizes; (void)n_in; (void)out_size;

    const size_t NKV = (size_t)Bb * Ss * Dd;                 // elements per K/V tensor
    const size_t need = NKV * 3 * sizeof(_Float16);          // Khi + Klo + Vt

    if (ws_size >= need) {
        _Float16* Khi = (_Float16*)d_ws;
        _Float16* Klo = Khi + NKV;
        _Float16* Vt = Klo + NKV;
        hipLaunchKernelGGL(prep_f16s, dim3(KP_BLOCKS + VT_BLOCKS), dim3(256), 0, stream,
                           k, v, Khi, Klo, Vt);
        hipLaunchKernelGGL(attn_fwd_v13, dim3(Bb * (Ss / QBLK)), dim3(512), 0, stream,
                           q, inv_scale, Khi, Klo, Vt, out);
    } else {
        hipLaunchKernelGGL(attn_fwd_fallback, dim3(Bb * 64), dim3(256), 0, stream,
                           q, k, v, inv_scale, out);
    }
}

// Round 14
// 169.267 us; speedup vs baseline: 2.4467x; 1.0368x over previous
//
#include <hip/hip_runtime.h>
#include <hip/hip_bf16.h>

typedef float f32x4 __attribute__((ext_vector_type(4)));
typedef float f32x16 __attribute__((ext_vector_type(16)));
typedef _Float16 half8 __attribute__((ext_vector_type(8)));
typedef __bf16 bf16x8 __attribute__((ext_vector_type(8)));
typedef __bf16 bf16x4 __attribute__((ext_vector_type(4)));
typedef unsigned short ushort_t;

constexpr int Bb = 16, Ss = 4096, Dd = 64;
constexpr int KBLK = 32, QBLK = 128;
constexpr int NT = Ss / KBLK;   // 128
constexpr float kLOG2E = 1.44269504088896340736f;
constexpr float DEFER_THR = 10.0f;   // exp2(10)=1024 max P; fp16-safe

constexpr int KP_BLOCKS = (Bb * Ss * Dd / 8) / 256;      // 2048
constexpr int VT_BLOCKS = (Bb * Dd * (Ss / 32)) / 256;   // 512

#define GLOAD_LDS16(gp, lp)                                                              \
    __builtin_amdgcn_global_load_lds(                                                    \
        (const __attribute__((address_space(1))) void*)(gp),                             \
        (__attribute__((address_space(3))) void*)(lp), 16, 0, 0)

// ------- pre-pass: K -> f16 hi/lo [b][s][d]; V -> Vt f16 [b][d][s] (round-6 verified) -
__global__ __launch_bounds__(256)
void prep_f16s(const float* __restrict__ K, const float* __restrict__ V,
               _Float16* __restrict__ Khi, _Float16* __restrict__ Klo,
               _Float16* __restrict__ Vt)
{
    const int bid = blockIdx.x;
    if (bid < KP_BLOCKS) {
        const size_t idx = ((size_t)bid * 256 + threadIdx.x) * 8;
        const float4 a = *reinterpret_cast<const float4*>(K + idx);
        const float4 c = *reinterpret_cast<const float4*>(K + idx + 4);
        float xs[8] = {a.x, a.y, a.z, a.w, c.x, c.y, c.z, c.w};
        half8 h8, l8;
#pragma unroll
        for (int i = 0; i < 8; ++i) {
            const _Float16 h = (_Float16)xs[i];
            h8[i] = h;
            l8[i] = (_Float16)(xs[i] - (float)h);
        }
        *reinterpret_cast<half8*>(Khi + idx) = h8;
        *reinterpret_cast<half8*>(Klo + idx) = l8;
    } else {
        const int t = (bid - KP_BLOCKS) * 256 + threadIdx.x;
        const int d = t & 63;
        const int s32 = (t >> 6) & (Ss / 32 - 1);
        const int b = t >> 13;
        const float* vp = V + ((size_t)b * Ss + (size_t)s32 * 32) * Dd + d;
        __align__(16) _Float16 ob[32];
#pragma unroll
        for (int j = 0; j < 32; ++j) ob[j] = (_Float16)vp[(size_t)j * Dd];
        _Float16* op = Vt + ((size_t)b * Dd + d) * Ss + (size_t)s32 * 32;
#pragma unroll
        for (int j8 = 0; j8 < 4; ++j8)
            *reinterpret_cast<half8*>(op + j8 * 8) = *reinterpret_cast<half8*>(ob + j8 * 8);
    }
}

union H8 { half8 h; unsigned int u[4]; };

// ------- main v14: round-6 v5 (163us best-known) + conflict-free V swizzle ------------
// 8 waves (512 thr): wave w = (qg = w>>1) q-group (32 rows of 128), (p = w&1) k-parity.
// Grid 512 blocks = exactly 2 blocks/CU; 16 waves/CU = 4/SIMD.
// LDS: 4 slots x (Khi 4K + Klo 4K + Vt 4K) = 48KB; merge epilogue reuses it.
// ONLY change vs v5: V swizzle uses (d>>1)&3 (r7/r10/r13-verified, conflicts 2.1e7->6e6).
__global__ __launch_bounds__(512, 4)
void attn_fwd_v14(const float* __restrict__ Q, const float* __restrict__ inv_scale,
                  const _Float16* __restrict__ Khi, const _Float16* __restrict__ Klo,
                  const _Float16* __restrict__ Vt, float* __restrict__ Out)
{
    __shared__ __align__(16) unsigned char smem[48 * 1024];

    const int tid = threadIdx.x;
    const int lane = tid & 63;
    const int w = tid >> 6;
    const int p = w & 1;
    const int qg = w >> 1;          // 0..3
    const int l31 = lane & 31;
    const int hi = lane >> 5;

    // T1 XCD swizzle: 512 blocks -> each XCD owns 64 consecutive (2 batches)
    const int bid = (blockIdx.x & 7) * 64 + (blockIdx.x >> 3);
    const int b = bid >> 5;
    const int q0 = (bid & 31) * QBLK;

    const _Float16* KhB = Khi + (size_t)b * Ss * Dd;
    const _Float16* KlB = Klo + (size_t)b * Ss * Dd;
    const _Float16* VB = Vt + (size_t)b * Dd * Ss;

    // staging: linear LDS dest, swizzle pre-applied on the GLOBAL source (rule #21).
    // waves 0-3 stage Khi, waves 4-7 stage Klo+Vt.
    const int c = tid & 255;
    const int kk = c >> 3;
    const int ksrc = kk * Dd + (((c & 7) ^ (kk & 7)) << 3);
    const int dd_ = c >> 2;
    const size_t vsrc = (size_t)dd_ * Ss + (((c & 3) ^ ((dd_ >> 1) & 3)) << 3);

#define STAGE(t)                                                                            \
    do {                                                                                    \
        const int _sl = (t) & 3;                                                            \
        if (tid < 256) {                                                                    \
            GLOAD_LDS16(KhB + (size_t)(t) * (KBLK * Dd) + ksrc,                             \
                        smem + _sl * 4096 + c * 16);                                        \
            GLOAD_LDS16(KlB + (size_t)(t) * (KBLK * Dd) + ksrc,                             \
                        smem + 16384 + _sl * 4096 + c * 16);                                \
        } else {                                                                            \
            GLOAD_LDS16(VB + (size_t)(t) * KBLK + vsrc,                                     \
                        smem + 32768 + _sl * 4096 + c * 16);                                \
        }                                                                                   \
    } while (0)

    STAGE(0);
    STAGE(1);

    // LDS read byte-offsets (swizzled), constant per thread
    int koff[4], voff[4];
#pragma unroll
    for (int ks = 0; ks < 4; ++ks)
        koff[ks] = l31 * 128 + ((((ks << 1) + hi) ^ (l31 & 7)) << 4);
#pragma unroll
    for (int i = 0; i < 4; ++i) {   // i = dblk*2 + ks ; conflict-free V swizzle
        const int d = (i >> 1) * 32 + l31;
        voff[i] = d * 64 + (((((i & 1) << 1) + hi) ^ ((d >> 1) & 3)) << 4);
    }

    // Q fragments f16 hi/lo, scale*log2e folded; lane: col q = l31, d = ks*16 + hi*8 ..+8
    H8 qhi[4], qlo[4];
    {
        const float s2 = (1.0f / inv_scale[0]) * kLOG2E;
        const float* qrow = Q + ((size_t)b * Ss + q0 + qg * 32 + l31) * Dd;
#pragma unroll
        for (int ks = 0; ks < 4; ++ks) {
            const int d0 = ks * 16 + hi * 8;
            const float4 a = *reinterpret_cast<const float4*>(qrow + d0);
            const float4 cc = *reinterpret_cast<const float4*>(qrow + d0 + 4);
            float xs[8] = {a.x, a.y, a.z, a.w, cc.x, cc.y, cc.z, cc.w};
#pragma unroll
            for (int i = 0; i < 8; ++i) {
                const float x = xs[i] * s2;
                const _Float16 h = (_Float16)x;
                qhi[ks].h[i] = h;
                qlo[ks].h[i] = (_Float16)(x - (float)h);
            }
        }
    }

    f32x16 O0, O1;
#pragma unroll
    for (int r = 0; r < 16; ++r) { O0[r] = 0.f; O1[r] = 0.f; }
    float m_run = -INFINITY, l_run = 0.f;

    __syncthreads();   // tiles 0,1 resident (barrier drains vmcnt)

    for (int it = 0; it < NT / 2; ++it) {
        const int t = 2 * it + p;
        const unsigned char* khbase = smem + (t & 3) * 4096;
        const unsigned char* klbase = smem + 16384 + (t & 3) * 4096;
        const unsigned char* vbase = smem + 32768 + (t & 3) * 4096;

        if (it < NT / 2 - 1) { STAGE(2 * it + 2); STAGE(2 * it + 3); }

        // ---- S^T = K·Q^T (32k x 32q), split-precision fp16 (hi*hi + lo*hi + hi*lo) ----
        f32x16 S;
#pragma unroll
        for (int r = 0; r < 16; ++r) S[r] = 0.f;
#pragma unroll
        for (int ks = 0; ks < 4; ++ks) {
            const half8 kh = *reinterpret_cast<const half8*>(khbase + koff[ks]);
            const half8 kl = *reinterpret_cast<const half8*>(klbase + koff[ks]);
            S = __builtin_amdgcn_mfma_f32_32x32x16_f16(kh, qhi[ks].h, S, 0, 0, 0);
            S = __builtin_amdgcn_mfma_f32_32x32x16_f16(kl, qhi[ks].h, S, 0, 0, 0);
            S = __builtin_amdgcn_mfma_f32_32x32x16_f16(kh, qlo[ks].h, S, 0, 0, 0);
        }
        // lane owns col q=l31; rows k = (r&3) + 8*(r>>2) + 4*hi (16 of 32; rest in lane^32)

        // ---- online softmax (log2 domain), defer-max ----
        float tmax = S[0];
#pragma unroll
        for (int r = 1; r < 16; ++r) tmax = fmaxf(tmax, S[r]);
        tmax = fmaxf(tmax, __shfl_xor(tmax, 32));

        float fac = 1.0f;
        if (__any(tmax > m_run + DEFER_THR)) {
            const float m_new = fmaxf(m_run, tmax);
            fac = __builtin_amdgcn_exp2f(m_run - m_new);
            m_run = m_new;
#pragma unroll
            for (int r = 0; r < 16; ++r) { O0[r] *= fac; O1[r] *= fac; }
        }

        float tsum = 0.f;
#pragma unroll
        for (int r = 0; r < 16; ++r) {
            S[r] = __builtin_amdgcn_exp2f(S[r] - m_run);
            tsum += S[r];
        }
        tsum += __shfl_xor(tsum, 32);
        l_run = l_run * fac + tsum;

        // ---- pack P to f16 words, cross-half exchange to form B-fragments ----
        unsigned int wd[8];
#pragma unroll
        for (int j = 0; j < 8; ++j) {
            const auto h2 = __builtin_amdgcn_cvt_pkrtz(S[2 * j], S[2 * j + 1]);
            wd[j] = __builtin_bit_cast(unsigned int, h2);
        }
        auto xhalf = [&](unsigned int& a, unsigned int& cx) {
            const unsigned int y = hi ? a : cx;
            const unsigned int sy = __shfl_xor(y, 32);
            const unsigned int na = hi ? sy : a;
            const unsigned int nc = hi ? cx : sy;
            a = na; cx = nc;
        };
        xhalf(wd[0], wd[2]);
        xhalf(wd[1], wd[3]);
        xhalf(wd[4], wd[6]);
        xhalf(wd[5], wd[7]);

        H8 pf0, pf1;
        pf0.u[0] = wd[0]; pf0.u[1] = wd[1]; pf0.u[2] = wd[2]; pf0.u[3] = wd[3];
        pf1.u[0] = wd[4]; pf1.u[1] = wd[5]; pf1.u[2] = wd[6]; pf1.u[3] = wd[7];

        // ---- O^T += V^T · P  (C: col = q = l31, row = d) ----
        O0 = __builtin_amdgcn_mfma_f32_32x32x16_f16(
            *reinterpret_cast<const half8*>(vbase + voff[0]), pf0.h, O0, 0, 0, 0);
        O0 = __builtin_amdgcn_mfma_f32_32x32x16_f16(
            *reinterpret_cast<const half8*>(vbase + voff[1]), pf1.h, O0, 0, 0, 0);
        O1 = __builtin_amdgcn_mfma_f32_32x32x16_f16(
            *reinterpret_cast<const half8*>(vbase + voff[2]), pf0.h, O1, 0, 0, 0);
        O1 = __builtin_amdgcn_mfma_f32_32x32x16_f16(
            *reinterpret_cast<const half8*>(vbase + voff[3]), pf1.h, O1, 0, 0, 0);

        __syncthreads();   // staged tiles ready; slots free for reuse
    }

    // ---- merge k-parity pairs (wave p=1 -> LDS; wave p=0 combines, stores) ----
    float* mO = (float*)smem;                 // [qg][dblk][rr][256] : 32KB (reuses slots)
    float* ml = (float*)(smem + 32768);       // [qg][{m,l}][32] : 1KB

    if (p == 1) {
#pragma unroll
        for (int dblk = 0; dblk < 2; ++dblk)
#pragma unroll
            for (int rr = 0; rr < 4; ++rr) {
                f32x4 v;
                if (dblk == 0) {
                    v[0] = O0[rr * 4 + 0]; v[1] = O0[rr * 4 + 1];
                    v[2] = O0[rr * 4 + 2]; v[3] = O0[rr * 4 + 3];
                } else {
                    v[0] = O1[rr * 4 + 0]; v[1] = O1[rr * 4 + 1];
                    v[2] = O1[rr * 4 + 2]; v[3] = O1[rr * 4 + 3];
                }
                *reinterpret_cast<f32x4*>(mO + (((qg * 2 + dblk) * 4 + rr) << 8) + lane * 4) = v;
            }
        if (hi == 0) {
            ml[qg * 64 + l31] = m_run;
            ml[qg * 64 + 32 + l31] = l_run;
        }
    }
    __syncthreads();
    if (p == 0) {
        const float m1 = ml[qg * 64 + l31];
        const float l1 = ml[qg * 64 + 32 + l31];
        const float mm = fmaxf(m_run, m1);
        float f0 = __builtin_amdgcn_exp2f(m_run - mm);
        float f1 = __builtin_amdgcn_exp2f(m1 - mm);
        const float inv = 1.0f / (l_run * f0 + l1 * f1);
        f0 *= inv; f1 *= inv;
        float* orow = Out + ((size_t)b * Ss + q0 + qg * 32 + l31) * Dd;
#pragma unroll
        for (int dblk = 0; dblk < 2; ++dblk)
#pragma unroll
            for (int rr = 0; rr < 4; ++rr) {
                const f32x4 ov = *reinterpret_cast<const f32x4*>(
                    mO + (((qg * 2 + dblk) * 4 + rr) << 8) + lane * 4);
                f32x4 res;
#pragma unroll
                for (int j = 0; j < 4; ++j) {
                    const float mine = (dblk == 0) ? O0[rr * 4 + j] : O1[rr * 4 + j];
                    res[j] = mine * f0 + ov[j] * f1;
                }
                // d = dblk*32 + 8*rr + 4*hi + j
                *reinterpret_cast<f32x4*>(orow + dblk * 32 + rr * 8 + hi * 4) = res;
            }
    }
#undef STAGE
}

// ---------------- fallback (validated round-1 kernel) if workspace too small ---------
__global__ __launch_bounds__(256)
void attn_fwd_fallback(const float* __restrict__ Q, const float* __restrict__ K,
                       const float* __restrict__ V, const float* __restrict__ inv_scale,
                       float* __restrict__ Out)
{
    __shared__ __align__(16) ushort_t sKhi[KBLK * Dd];
    __shared__ __align__(16) ushort_t sKlo[KBLK * Dd];
    __shared__ __align__(16) ushort_t sVt[Dd * KBLK];
    __shared__ __align__(16) ushort_t sP[4][16 * KBLK];

    const int tid = threadIdx.x;
    const int lane = tid & 63;
    const int w = tid >> 6;
    const int q15 = lane & 15;
    const int g = lane >> 4;
    const int b = blockIdx.x >> 6;
    const int q0 = (blockIdx.x & 63) * 64;
    const float scale = 1.0f / inv_scale[0];

    const float* qptr = Q + (((size_t)b * Ss) + q0 + w * 16 + q15) * Dd;
    bf16x8 qhi[2], qlo[2];
#pragma unroll
    for (int ds = 0; ds < 2; ++ds) {
        const float4 f0 = *reinterpret_cast<const float4*>(qptr + ds * 32 + g * 8);
        const float4 f1 = *reinterpret_cast<const float4*>(qptr + ds * 32 + g * 8 + 4);
        float xs[8] = {f0.x, f0.y, f0.z, f0.w, f1.x, f1.y, f1.z, f1.w};
#pragma unroll
        for (int i = 0; i < 8; ++i) {
            __bf16 h = (__bf16)xs[i];
            qhi[ds][i] = h;
            qlo[ds][i] = (__bf16)(xs[i] - (float)h);
        }
    }
    const int krs = tid >> 3;
    const int kc8 = (tid & 7) * 8;
    const int kidx = krs * Dd + (kc8 ^ ((krs & 7) << 3));
    const float* kbase = K + ((size_t)b * Ss) * Dd;
    const int vd = tid & 63;
    const int vk8 = (tid >> 6) * 8;
    const int vidx = vd * KBLK + (vk8 ^ ((vd & 3) << 3));
    const float* vbase = V + ((size_t)b * Ss) * Dd;

    f32x4 Oacc[4];
#pragma unroll
    for (int dt = 0; dt < 4; ++dt)
#pragma unroll
        for (int r = 0; r < 4; ++r) Oacc[dt][r] = 0.f;
    float m_run = -INFINITY, l_run = 0.f;

    for (int k0 = 0; k0 < Ss; k0 += KBLK) {
        {
            const float* p0 = kbase + (size_t)(k0 + krs) * Dd + kc8;
            const float4 a = *reinterpret_cast<const float4*>(p0);
            const float4 c = *reinterpret_cast<const float4*>(p0 + 4);
            float xs[8] = {a.x, a.y, a.z, a.w, c.x, c.y, c.z, c.w};
            bf16x8 h8, l8;
#pragma unroll
            for (int i = 0; i < 8; ++i) {
                __bf16 h = (__bf16)xs[i];
                h8[i] = h;
                l8[i] = (__bf16)(xs[i] - (float)h);
            }
            *reinterpret_cast<bf16x8*>(&sKhi[kidx]) = h8;
            *reinterpret_cast<bf16x8*>(&sKlo[kidx]) = l8;
        }
        {
            bf16x8 v8;
#pragma unroll
            for (int j = 0; j < 8; ++j) v8[j] = (__bf16)vbase[(size_t)(k0 + vk8 + j) * Dd + vd];
            *reinterpret_cast<bf16x8*>(&sVt[vidx]) = v8;
        }
        __syncthreads();

        float z[2][4];
#pragma unroll
        for (int t = 0; t < 2; ++t) {
            const int krow = t * 16 + q15;
            f32x4 acc;
            acc[0] = acc[1] = acc[2] = acc[3] = 0.f;
#pragma unroll
            for (int ds = 0; ds < 2; ++ds) {
                const int ci = (ds * 32 + g * 8) ^ ((krow & 7) << 3);
                const bf16x8 kh = *reinterpret_cast<const bf16x8*>(&sKhi[krow * Dd + ci]);
                const bf16x8 kl = *reinterpret_cast<const bf16x8*>(&sKlo[krow * Dd + ci]);
                acc = __builtin_amdgcn_mfma_f32_16x16x32_bf16(kh, qhi[ds], acc, 0, 0, 0);
                acc = __builtin_amdgcn_mfma_f32_16x16x32_bf16(kl, qhi[ds], acc, 0, 0, 0);
                acc = __builtin_amdgcn_mfma_f32_16x16x32_bf16(kh, qlo[ds], acc, 0, 0, 0);
            }
#pragma unroll
            for (int r = 0; r < 4; ++r) z[t][r] = acc[r] * scale;
        }

        float tmax = z[0][0];
#pragma unroll
        for (int t = 0; t < 2; ++t)
#pragma unroll
            for (int r = 0; r < 4; ++r) tmax = fmaxf(tmax, z[t][r]);
        tmax = fmaxf(tmax, __shfl_xor(tmax, 16));
        tmax = fmaxf(tmax, __shfl_xor(tmax, 32));
        const float m_new = fmaxf(m_run, tmax);

        float pz[2][4];
        float tsum = 0.f;
#pragma unroll
        for (int t = 0; t < 2; ++t)
#pragma unroll
            for (int r = 0; r < 4; ++r) {
                const float e = __builtin_amdgcn_exp2f((z[t][r] - m_new) * kLOG2E);
                pz[t][r] = e;
                tsum += e;
            }
        tsum += __shfl_xor(tsum, 16);
        tsum += __shfl_xor(tsum, 32);
        const float fac = __builtin_amdgcn_exp2f((m_run - m_new) * kLOG2E);
        l_run = l_run * fac + tsum;
        m_run = m_new;

#pragma unroll
        for (int t = 0; t < 2; ++t) {
            bf16x4 pb;
#pragma unroll
            for (int r = 0; r < 4; ++r) pb[r] = (__bf16)pz[t][r];
            const int pidx = q15 * KBLK + ((t * 16 + g * 4) ^ ((q15 & 3) << 3));
            *reinterpret_cast<bf16x4*>(&sP[w][pidx]) = pb;
        }
        {
            const float fr0 = __shfl(fac, g * 4 + 0);
            const float fr1 = __shfl(fac, g * 4 + 1);
            const float fr2 = __shfl(fac, g * 4 + 2);
            const float fr3 = __shfl(fac, g * 4 + 3);
#pragma unroll
            for (int dt = 0; dt < 4; ++dt) {
                Oacc[dt][0] *= fr0; Oacc[dt][1] *= fr1;
                Oacc[dt][2] *= fr2; Oacc[dt][3] *= fr3;
            }
        }
        const int paidx = q15 * KBLK + ((g * 8) ^ ((q15 & 3) << 3));
        const bf16x8 pa = *reinterpret_cast<const bf16x8*>(&sP[w][paidx]);
#pragma unroll
        for (int dt = 0; dt < 4; ++dt) {
            const int dd = dt * 16 + q15;
            const bf16x8 vf =
                *reinterpret_cast<const bf16x8*>(&sVt[dd * KBLK + ((g * 8) ^ ((dd & 3) << 3))]);
            Oacc[dt] = __builtin_amdgcn_mfma_f32_16x16x32_bf16(pa, vf, Oacc[dt], 0, 0, 0);
        }
        __syncthreads();
    }

    const float invl = 1.0f / l_run;
    float il[4];
#pragma unroll
    for (int r = 0; r < 4; ++r) il[r] = __shfl(invl, g * 4 + r);
    float* obase = Out + (((size_t)b * Ss) + q0 + w * 16) * Dd;
#pragma unroll
    for (int dt = 0; dt < 4; ++dt)
#pragma unroll
        for (int r = 0; r < 4; ++r)
            obase[(size_t)(g * 4 + r) * Dd + dt * 16 + q15] = Oacc[dt][r] * il[r];
}

extern "C" void kernel_launch(void* const* d_in, const int* in_sizes, int n_in,
                              void* d_out, int out_size, void* d_ws, size_t ws_size,
                              hipStream_t stream)
{
    const float* q = (const float*)d_in[0];
    const float* k = (const float*)d_in[1];
    const float* v = (const float*)d_in[2];
    const float* inv_scale = (const float*)d_in[3];
    float* out = (float*)d_out;
    (void)in_sizes; (void)n_in; (void)out_size;

    const size_t NKV = (size_t)Bb * Ss * Dd;                 // elements per K/V tensor
    const size_t need = NKV * 3 * sizeof(_Float16);          // Khi + Klo + Vt

    if (ws_size >= need) {
        _Float16* Khi = (_Float16*)d_ws;
        _Float16* Klo = Khi + NKV;
        _Float16* Vt = Klo + NKV;
        hipLaunchKernelGGL(prep_f16s, dim3(KP_BLOCKS + VT_BLOCKS), dim3(256), 0, stream,
                           k, v, Khi, Klo, Vt);
        hipLaunchKernelGGL(attn_fwd_v14, dim3(Bb * (Ss / QBLK)), dim3(512), 0, stream,
                           q, inv_scale, Khi, Klo, Vt, out);
    } else {
        hipLaunchKernelGGL(attn_fwd_fallback, dim3(Bb * 64), dim3(256), 0, stream,
                           q, k, v, inv_scale, out);
    }
}